// Round 1
// baseline (252.343 us; speedup 1.0000x reference)
//
#include <hip/hip_runtime.h>

// BioConvolution: 256 per-location GEMMs, C_l(64x128) = A_l(64x1024)*B_l(1024x128)+bias, ReLU
// X layout [n][h][w][ch] strides: n=262144, h=4096, w=64, ch=1.
// A_l[n][k] = X[n, r*4+i, c*4+j, ch], k = i*256 + j*64 + ch
//   -> offset = n*262144 + r*16384 + i*4096 + c*256 + j*64 + ch
// B_l[k][f] = Fw[l*131072 + k*128 + f]
//
// R5: occupancy fix. R4 ran 1 wave/SIMD (grid 1024 x 64thr) -> 94% vmem stall
// (6.5k cyc/step vs ~300 cyc of work; MfmaUtil 1.8%, VALUBusy 6%, Occ 10%).
// Now: 256-thread blocks, 4 waves, each wave owns 16 rows (former mb) with the
// SAME barrier-free wave-autonomous pipeline (A: global->reg; B: global->reg->
// bf16-pack->wave-PRIVATE LDS quarter; all ordering wave-internal s_waitcnt).
// Grid stays 1024 -> 4 blocks/CU = 16 waves/CU = 4 waves/SIMD (4x latency hiding).
// The 4 waves of a block read the same B slice -> dupes hit L1, L2 traffic flat.
// XCD-aware mapping: all 16 waves... all 4 fq-blocks of a location on one XCD.

typedef __bf16 bf16x8 __attribute__((ext_vector_type(8)));
typedef float f32x4 __attribute__((ext_vector_type(4)));

#define SBQ 36  // LDS B row stride in words (16 kp-rows per stage, +4 pad)

__device__ __forceinline__ unsigned pack2(float a, float b) {
  __bf16 lo = (__bf16)a, hi = (__bf16)b;
  return (unsigned)__builtin_bit_cast(unsigned short, lo) |
         ((unsigned)__builtin_bit_cast(unsigned short, hi) << 16);
}
__device__ __forceinline__ bf16x8 cvt8(float4 lo, float4 hi) {
  uint4 v;
  v.x = pack2(lo.x, lo.y);
  v.y = pack2(lo.z, lo.w);
  v.z = pack2(hi.x, hi.y);
  v.w = pack2(hi.z, hi.w);
  return __builtin_bit_cast(bf16x8, v);
}

__global__ __launch_bounds__(256, 4) void bioconv_wave4(
    const float* __restrict__ X, const float* __restrict__ Fw,
    const float* __restrict__ bias, float* __restrict__ out) {
  const int bx = blockIdx.x;
  // XCD-aware placement (assumes HW round-robin: XCD = launch_idx & 7).
  // Each XCD gets 32 whole locations; the 4 fq-blocks of a location are
  // adjacent in per-XCD dispatch order -> shared X patch stays in that L2.
  // If the mapping assumption is wrong this is only a permutation (correct).
  const int xcd = bx & 7;
  const int idx = bx >> 3;             // 0..127 within XCD
  const int l = xcd * 32 + (idx >> 2); // location 0..255
  const int fq = idx & 3;              // f quarter
  const int r = l >> 4, c = l & 15;
  const int tid = threadIdx.x;
  const int wave = tid >> 6;  // rowq 0..3: this wave owns rows wave*16..wave*16+15
  const int lane = tid & 63;
  const int q = lane >> 4, nl = lane & 15;

  // 4 wave-private B stages, 4.6 KB each -> 18.4 KB/block, 73.7 KB/CU at 4 blocks
  __shared__ __align__(16) unsigned Bs[4][2][16 * SBQ];

  // A row base: row = wave*16 + nl; q*8 = k sub-offset within a 32-ch half-run
  const float* pA =
      X + (size_t)(wave * 16 + nl) * 262144 + r * 16384 + c * 256 + q * 8;

  // B: kp0 = lane>>3 (0..7), col chunk (lane&7)*4 within the 32-col slice
  const float* pB = Fw + (size_t)l * 131072 + fq * 32 + (lane >> 3) * 256 + (lane & 7) * 4;
  unsigned* const wpB = (unsigned*)Bs[wave] + ((lane >> 3) * SBQ + (lane & 7) * 4);

  float4 aR[2][2];  // A prefetch ring, depth 2 (1 step = 2 float4/lane)
  float4 bR[3][4];  // B prefetch ring, depth 3 (1 step = 4 float4/lane)
  f32x4 acc[2];
  acc[0] = (f32x4){0.f, 0.f, 0.f, 0.f};
  acc[1] = (f32x4){0.f, 0.f, 0.f, 0.f};

  auto issueA = [&](int s, int ring) {
    const int p = s >> 1;  // pixel index 0..15: i = p>>2, j = p&3
    const int off = (p >> 2) * 4096 + (p & 3) * 64 + (s & 1) * 32;
    aR[ring][0] = *(const float4*)(pA + off);
    aR[ring][1] = *(const float4*)(pA + off + 4);
  };
  auto issueB = [&](int s, int ring) {
#pragma unroll
    for (int rep = 0; rep < 2; ++rep) {
      const float* g = pB + s * 4096 + rep * 2048;
      bR[ring][rep * 2] = *(const float4*)(g);            // k = s*32 + 2*kp
      bR[ring][rep * 2 + 1] = *(const float4*)(g + 128);  // k odd
    }
  };
  auto writeB = [&](int s, int ring) {
    unsigned* wp = wpB + (s & 1) * (16 * SBQ);
#pragma unroll
    for (int rep = 0; rep < 2; ++rep) {
      float4 e0 = bR[ring][rep * 2], e1 = bR[ring][rep * 2 + 1];
      uint4 v;  // word = bf16 B[2kp][col] | bf16 B[2kp+1][col] << 16
      v.x = pack2(e0.x, e1.x);
      v.y = pack2(e0.y, e1.y);
      v.z = pack2(e0.z, e1.z);
      v.w = pack2(e0.w, e1.w);
      *(uint4*)(wp + rep * 8 * SBQ) = v;
    }
  };

  // ---- pipeline preamble ----
  issueA(0, 0);
  issueB(0, 0);
  issueA(1, 1);
  issueB(1, 1);
  issueB(2, 2);
  writeB(0, 0);  // waits bR[0]; fills LDS buf 0

  // ---- 32 fully-unrolled K-steps (BK=32), no barriers ----
#pragma unroll
  for (int s = 0; s < 32; ++s) {
    if (s + 3 < 32) issueB(s + 3, (s + 3) % 3);
    if (s + 1 < 32) writeB(s + 1, (s + 1) % 3);  // -> buf[(s+1)&1]; reads of buf[s&1] unaffected

    bf16x8 af = cvt8(aR[s & 1][0], aR[s & 1][1]);  // waits aR[s&1]
    if (s + 2 < 32) issueA(s + 2, s & 1);

#pragma unroll
    for (int fb = 0; fb < 2; ++fb) {
      const unsigned* bp = &Bs[wave][s & 1][(q * 4) * SBQ + fb * 16 + nl];
      uint4 v;
      v.x = bp[0];
      v.y = bp[SBQ];
      v.z = bp[2 * SBQ];
      v.w = bp[3 * SBQ];
      bf16x8 bfr = __builtin_bit_cast(bf16x8, v);
      acc[fb] = __builtin_amdgcn_mfma_f32_16x16x32_bf16(af, bfr, acc[fb], 0, 0, 0);
    }
  }

  // ---- epilogue: bias + ReLU; D layout row = q*4+reg, col = nl ----
#pragma unroll
  for (int fb = 0; fb < 2; ++fb) {
    const int f = fq * 32 + fb * 16 + nl;
    const float bv = bias[f];
    float* ob = out + (size_t)l * 128 + f;
#pragma unroll
    for (int v = 0; v < 4; ++v) {
      const int row = wave * 16 + q * 4 + v;
      ob[(size_t)row * 32768] = fmaxf(acc[fb][v] + bv, 0.f);
    }
  }
}

extern "C" void kernel_launch(void* const* d_in, const int* in_sizes, int n_in,
                              void* d_out, int out_size, void* d_ws, size_t ws_size,
                              hipStream_t stream) {
  const float* X = (const float*)d_in[0];
  const float* Fw = (const float*)d_in[1];
  const float* bias = (const float*)d_in[2];
  float* out = (float*)d_out;
  bioconv_wave4<<<1024, 256, 0, stream>>>(X, Fw, bias, out);
}

// Round 2
// 238.946 us; speedup vs baseline: 1.0561x; 1.0561x over previous
//
#include <hip/hip_runtime.h>

// BioConvolution: 256 per-location GEMMs, C_l(64x128) = A_l(64x1024)*B_l(1024x128)+bias, ReLU
// X layout [n][h][w][ch]: offset = n*262144 + (r*4+i)*4096 + (c*4+j)*64 + ch
//   -> for fixed (n,i): k-run j*64+ch is 256 CONTIGUOUS floats.
// B_l[k][f] = Fw[l*131072 + k*128 + f] (fully contiguous).
//
// R6: block-cooperative staging. R5 showed occupancy 3x (10->31%) with ZERO time
// gain and 2x the L1-level bytes -> memory path is a demand-rate wall, not latency.
// Fix: cut demand 3x. Grid 512 = (l, fhalf); block 512 thr (8 waves) computes the
// 64x64 tile; A,B staged ONCE per block (was 4x dup B per-wave + 4x dup A per-fq).
// BK=128, double-buffered LDS, ONE barrier per K-step, reg-staged prefetch with
// 1-iteration slack. A in LDS as bf16 XOR-swizzled (row stride 256B would be a
// 16-way conflict on ds_read_b128; byte ^= (row&7)<<4 makes it exactly-8 = free).
// B in LDS as k-paired words [kp][col], pad 68 (verified layout from R4/R5).
// MFMA fragment conventions copied from the harness-verified R4/R5 kernel.

typedef __bf16 bf16x8 __attribute__((ext_vector_type(8)));
typedef float f32x4 __attribute__((ext_vector_type(4)));

__device__ __forceinline__ unsigned pack2(float a, float b) {
  __bf16 lo = (__bf16)a, hi = (__bf16)b;
  return (unsigned)__builtin_bit_cast(unsigned short, lo) |
         ((unsigned)__builtin_bit_cast(unsigned short, hi) << 16);
}

__global__ __launch_bounds__(512, 4) void bioconv_blk(
    const float* __restrict__ X, const float* __restrict__ Fw,
    const float* __restrict__ bias, float* __restrict__ out) {
  const int bx = blockIdx.x;
  // XCD-aware: both f-halves of a location land on the same XCD (l shared in L2).
  const int xcd = bx & 7;
  const int idx = bx >> 3;              // 0..63
  const int l = xcd * 32 + (idx >> 1);  // 0..255
  const int fh = idx & 1;               // f half: cols fh*64..fh*64+63
  const int r = l >> 4, c = l & 15;

  const int t = threadIdx.x;
  const int wave = t >> 6, lane = t & 63;
  const int q = lane >> 4, nl = lane & 15;
  const int m0 = (wave >> 1) * 16;  // wave's 16 output rows
  const int n0 = (wave & 1) * 32;   // wave's 32 output cols (within the 64-half)

  // A: [2][64 rows][128 k] bf16, XOR-swizzled -> 16 KB/buf
  // B: [2][64 kp][68 words] (word = B[2kp][col] | B[2kp+1][col]<<16) -> 17 KB/buf
  __shared__ __align__(16) unsigned short As[2][64 * 128];
  __shared__ __align__(16) unsigned Bs[2][64 * 68];

  // ---- staging assignments (all 512 threads) ----
  const int arow = t >> 3;   // A: row 0..63   | B: kp 0..63
  const int alane = t & 7;   // 8-lane groups -> 128 B contiguous global segments
  const float* gA = X + (size_t)arow * 262144 + r * 16384 + c * 256;
  const float* gB = Fw + (size_t)l * 131072 + fh * 64 + (size_t)arow * 256;

  float4 vA[4], vB[4];

  auto loadA = [&](int s) {
    const float* g = gA + (s >> 1) * 4096 + (s & 1) * 128;  // i = s>>1, half = s&1
#pragma unroll
    for (int rep = 0; rep < 4; ++rep)
      vA[rep] = *(const float4*)(g + (alane + rep * 8) * 4);
  };
  auto loadB = [&](int s) {
    const float* g = gB + s * 16384;  // k rows [s*128, s*128+128), 2 rows per kp
#pragma unroll
    for (int rep = 0; rep < 2; ++rep) {
      vB[rep * 2] = *(const float4*)(g + (alane + rep * 8) * 4);        // k = 2kp
      vB[rep * 2 + 1] = *(const float4*)(g + 128 + (alane + rep * 8) * 4);  // k = 2kp+1
    }
  };
  auto writeA = [&](int buf) {
    unsigned* base = (unsigned*)&As[buf][0];
#pragma unroll
    for (int rep = 0; rep < 4; ++rep) {
      const int f4 = alane + rep * 8;  // float4 index within row (k = 4*f4..+3)
      uint2 u;
      u.x = pack2(vA[rep].x, vA[rep].y);
      u.y = pack2(vA[rep].z, vA[rep].w);
      // word idx = row*64 + (f4*2 ^ ((row&7)<<2))  (byte ^= (row&7)<<4)
      *(uint2*)(base + arow * 64 + ((f4 * 2) ^ ((arow & 7) << 2))) = u;
    }
  };
  auto writeB = [&](int buf) {
    unsigned* base = (unsigned*)&Bs[buf][0];
#pragma unroll
    for (int rep = 0; rep < 2; ++rep) {
      const int f4 = alane + rep * 8;  // col group 4*f4..+3
      uint4 v;
      v.x = pack2(vB[rep * 2].x, vB[rep * 2 + 1].x);
      v.y = pack2(vB[rep * 2].y, vB[rep * 2 + 1].y);
      v.z = pack2(vB[rep * 2].z, vB[rep * 2 + 1].z);
      v.w = pack2(vB[rep * 2].w, vB[rep * 2 + 1].w);
      *(uint4*)(base + arow * 68 + f4 * 4) = v;  // kp = arow
    }
  };

  f32x4 acc[2];
  acc[0] = (f32x4){0.f, 0.f, 0.f, 0.f};
  acc[1] = (f32x4){0.f, 0.f, 0.f, 0.f};

  auto compute = [&](int buf) {
#pragma unroll
    for (int kk = 0; kk < 4; ++kk) {  // 4 x k32 within BK=128
      // A-frag: lane holds A[m0+nl][kk*32 + q*8 + j]  (verified convention)
      const unsigned short* ap =
          &As[buf][(m0 + nl) * 128 + ((kk * 32 + q * 8) ^ ((nl & 7) << 3))];
      bf16x8 af = *(const bf16x8*)ap;
#pragma unroll
      for (int fb = 0; fb < 2; ++fb) {
        // B-frag: lane holds B[kk*32 + q*8 + j][n0 + fb*16 + nl]
        const unsigned* bp =
            (const unsigned*)&Bs[buf][0] + (kk * 16 + q * 4) * 68 + n0 + fb * 16 + nl;
        uint4 v;
        v.x = bp[0];
        v.y = bp[68];
        v.z = bp[136];
        v.w = bp[204];
        bf16x8 bfr = __builtin_bit_cast(bf16x8, v);
        acc[fb] = __builtin_amdgcn_mfma_f32_16x16x32_bf16(af, bfr, acc[fb], 0, 0, 0);
      }
    }
  };

  // ---- pipeline: 8 K-steps of BK=128, one barrier per step ----
  loadA(0);
  loadB(0);
  writeA(0);
  writeB(0);
  loadA(1);
  loadB(1);
#pragma unroll
  for (int s = 0; s < 8; ++s) {
    __syncthreads();  // buf[s&1] fully written; buf[(s+1)&1] fully drained
    compute(s & 1);
    if (s + 1 < 8) {
      writeA((s + 1) & 1);
      writeB((s + 1) & 1);
    }
    if (s + 2 < 8) {
      loadA(s + 2);
      loadB(s + 2);
    }
  }

  // ---- epilogue: bias + ReLU; D row = m0 + q*4 + v, col = n0 + fb*16 + nl ----
#pragma unroll
  for (int fb = 0; fb < 2; ++fb) {
    const int f = fh * 64 + n0 + fb * 16 + nl;
    const float bv = bias[f];
    float* ob = out + (size_t)l * 128 + f;
#pragma unroll
    for (int v = 0; v < 4; ++v) {
      const int row = m0 + q * 4 + v;
      ob[(size_t)row * 32768] = fmaxf(acc[fb][v] + bv, 0.f);
    }
  }
}

extern "C" void kernel_launch(void* const* d_in, const int* in_sizes, int n_in,
                              void* d_out, int out_size, void* d_ws, size_t ws_size,
                              hipStream_t stream) {
  const float* X = (const float*)d_in[0];
  const float* Fw = (const float*)d_in[1];
  const float* bias = (const float*)d_in[2];
  float* out = (float*)d_out;
  bioconv_blk<<<512, 512, 0, stream>>>(X, Fw, bias, out);
}